// Round 7
// baseline (118.146 us; speedup 1.0000x reference)
//
#include <hip/hip_runtime.h>
#include <hip/hip_bf16.h>

typedef __bf16 bf16;
typedef __bf16 bf16x8 __attribute__((ext_vector_type(8)));
typedef __bf16 bf16x4 __attribute__((ext_vector_type(4)));
typedef float floatx4 __attribute__((ext_vector_type(4)));

// may_alias: LDS P-buffer is written as int (fp8 pack) and read as long
// (MFMA fragment) with no barrier between (wave-private). Without may_alias,
// TBAA lets the compiler reorder the ds_read above the ds_write (round-3 NaN).
typedef int    aint    __attribute__((may_alias));
typedef long   along   __attribute__((may_alias));

#define NPIX 4096
#define BATCH 4
#define LOG2E 1.4426950408889634f
// hT3 layout: [b][j>>5][c][j&31] bytes; 2048 B per j5-block, 262144 B per batch
#define HT_BATCH 262144

__device__ inline bf16x8 zero8() {
    bf16x8 v;
    #pragma unroll
    for (int i = 0; i < 8; ++i) v[i] = (bf16)0.0f;
    return v;
}

// ---------------------------------------------------------------------------
// Kernel 1: projections via MFMA.  X[16384x64] @ W[64x80] ->
//   fq [16384][8] bf16, gq [16384][8] bf16 (PRE-SCALED by log2e),
//   hT3 [4][128][64][32] fp8 e4m3 (MFMA-B-fragment-native tiling: one PV
//   bfrag = 512 contiguous bytes).
// ---------------------------------------------------------------------------
__global__ __launch_bounds__(256) void proj_kernel(
    const float* __restrict__ x,
    const float* __restrict__ w_f, const float* __restrict__ b_f,
    const float* __restrict__ w_g, const float* __restrict__ b_g,
    const float* __restrict__ w_h, const float* __restrict__ b_h,
    bf16* __restrict__ fq, bf16* __restrict__ gq, unsigned char* __restrict__ hT)
{
    __shared__ bf16 xs[64 * 72];
    __shared__ bf16 wt[80 * 72];
    __shared__ float bs[80];
    const int tid = threadIdx.x;
    const int p0 = blockIdx.x * 64;

    {   // stage x tile 64x64 f32 -> bf16
        const float4* xg = (const float4*)(x + (long)p0 * 64);
        #pragma unroll
        for (int it = 0; it < 4; ++it) {
            int i4 = tid + it * 256;
            float4 v = xg[i4];
            int row = i4 >> 4, c4 = (i4 & 15) * 4;
            bf16x4 pk;
            pk[0] = (bf16)v.x; pk[1] = (bf16)v.y; pk[2] = (bf16)v.z; pk[3] = (bf16)v.w;
            *(bf16x4*)(&xs[row * 72 + c4]) = pk;
        }
    }
    for (int idx = tid; idx < 80 * 64; idx += 256) {
        int n = idx >> 6, c = idx & 63;
        float v = (n < 8) ? w_f[c * 8 + n]
                : (n < 16) ? w_g[c * 8 + (n - 8)]
                : w_h[c * 64 + (n - 16)];
        wt[n * 72 + c] = (bf16)v;
    }
    if (tid < 80)
        bs[tid] = (tid < 8) ? b_f[tid] : (tid < 16) ? b_g[tid - 8] : b_h[tid - 16];
    __syncthreads();

    const int wv = tid >> 6, lane = tid & 63;
    const int quad = lane >> 4, l15 = lane & 15;
    const int b = blockIdx.x >> 6;
    const int n0pix = (p0 & (NPIX - 1)) + wv * 16 + quad * 4;  // pixel-in-batch

    bf16x8 a0 = *(const bf16x8*)(&xs[(wv * 16 + l15) * 72 + quad * 8]);
    bf16x8 a1 = *(const bf16x8*)(&xs[(wv * 16 + l15) * 72 + 32 + quad * 8]);

    #pragma unroll
    for (int nt = 0; nt < 5; ++nt) {
        float bias = bs[nt * 16 + l15];
        floatx4 acc = {bias, bias, bias, bias};
        bf16x8 b0 = *(const bf16x8*)(&wt[(nt * 16 + l15) * 72 + quad * 8]);
        bf16x8 b1 = *(const bf16x8*)(&wt[(nt * 16 + l15) * 72 + 32 + quad * 8]);
        acc = __builtin_amdgcn_mfma_f32_16x16x32_bf16(a0, b0, acc, 0, 0, 0);
        acc = __builtin_amdgcn_mfma_f32_16x16x32_bf16(a1, b1, acc, 0, 0, 0);
        if (nt == 0) {
            #pragma unroll
            for (int r = 0; r < 4; ++r) {
                long P = (long)p0 + wv * 16 + quad * 4 + r;
                if (l15 < 8) fq[P * 8 + l15] = (bf16)acc[r];
                else         gq[P * 8 + (l15 - 8)] = (bf16)(acc[r] * LOG2E);
            }
        } else {
            int c = nt * 16 + l15 - 16;
            int pk = __builtin_amdgcn_cvt_pk_fp8_f32(acc[0], acc[1], 0, false);
            pk     = __builtin_amdgcn_cvt_pk_fp8_f32(acc[2], acc[3], pk, true);
            // hT3[b][n0pix>>5][c][n0pix&31], 4 consecutive j bytes
            *(aint*)(hT + (long)b * HT_BATCH + (n0pix >> 5) * 2048
                     + c * 32 + (n0pix & 31)) = pk;
        }
    }
}

// ---------------------------------------------------------------------------
// Kernel 2: BARRIER-FREE fp8 MFMA flash attention partials.
// Grid 1024 = jsplit(4) x [B(4) x i-tiles(64 of 64 rows)]. Block 256 = 4
// waves, each wave fully independent (16 i rows, j-slice of 1024 = 8 tiles
// of 128). NO __syncthreads, NO LDS staging: F and Ht3 MFMA fragments are
// loaded directly from global (L1/L2-resident; hT3 tiling makes each PV
// bfrag one contiguous 512-B load). LDS only for the wave-private P
// round-trip (C-layout -> A-layout transpose), 8.7 KB/block.
// ---------------------------------------------------------------------------
__global__ __launch_bounds__(256) void attn_kernel(
    const bf16* __restrict__ fq, const bf16* __restrict__ gq,
    const unsigned char* __restrict__ hT, float* __restrict__ partial)
{
    __shared__ char smem[4 * 2176];
    const int tid  = threadIdx.x;
    const int wv   = tid >> 6, lane = tid & 63;
    const int quad = lane >> 4, l15 = lane & 15;
    const int js   = blockIdx.x >> 8;           // j-slice 0..3
    const int ib   = blockIdx.x & 255;
    const int b    = ib >> 6, it = ib & 63;
    const long rowbase = (long)b * NPIX + it * 64 + wv * 16;   // wave's 16 i rows
    const int jbase = js * 1024;

    // G fragment (bf16, pre-scaled by log2e): real k<8 in quad-0 lanes
    bf16x8 gfrag = zero8();
    if (lane < 16) gfrag = *(const bf16x8*)(gq + (rowbase + lane) * 8);

    const bf16* Fb = fq + ((long)b * NPIX + jbase) * 8;
    const unsigned char* Hb = hT + (long)b * HT_BATCH + (jbase >> 5) * 2048
                            + (l15 * 32 + quad * 8);   // per-lane part folded in

    floatx4 acc[5];                             // [0..3]=O channels, [4]=den
    #pragma unroll
    for (int nt = 0; nt < 5; ++nt) acc[nt] = (floatx4){0.f, 0.f, 0.f, 0.f};
    const along ones = 0x3838383838383838L;     // fp8 e4m3 1.0 x8
    char* Pw = smem + wv * 2176;                // wave-private P: 16 x 136 B

    for (int t = 0; t < 8; ++t) {
        // --- bfrag prefetch (global, contiguous 512B/instr): overlaps S ---
        along bfr[16];
        #pragma unroll
        for (int ks = 0; ks < 4; ++ks)
            #pragma unroll
            for (int nt = 0; nt < 4; ++nt)
                bfr[ks * 4 + nt] = *(const along*)(Hb + (t * 4 + ks) * 2048 + nt * 512);
        // --- S^T = F·G^T (bf16), exp2, pack fp8 -> P ---
        #pragma unroll
        for (int j8 = 0; j8 < 8; ++j8) {
            bf16x8 afrag = zero8();
            if (lane < 16) afrag = *(const bf16x8*)(Fb + (t * 128 + j8 * 16 + l15) * 8);
            floatx4 s = __builtin_amdgcn_mfma_f32_16x16x32_bf16(
                afrag, gfrag, (floatx4){0.f, 0.f, 0.f, 0.f}, 0, 0, 0);
            float e0 = __builtin_amdgcn_exp2f(s[0]);
            float e1 = __builtin_amdgcn_exp2f(s[1]);
            float e2 = __builtin_amdgcn_exp2f(s[2]);
            float e3 = __builtin_amdgcn_exp2f(s[3]);
            int pk = __builtin_amdgcn_cvt_pk_fp8_f32(e0, e1, 0, false);
            pk     = __builtin_amdgcn_cvt_pk_fp8_f32(e2, e3, pk, true);
            *(aint*)(Pw + l15 * 136 + j8 * 16 + quad * 4) = pk;
        }
        asm volatile("" ::: "memory");          // P writes before P reads
        // --- O += P·Ht, den += P·1 (fp8 MFMA, bfrags already in regs) ---
        #pragma unroll
        for (int ks = 0; ks < 4; ++ks) {
            along pfrag = *(const along*)(Pw + l15 * 136 + ks * 32 + quad * 8);
            #pragma unroll
            for (int nt = 0; nt < 4; ++nt)
                acc[nt] = __builtin_amdgcn_mfma_f32_16x16x32_fp8_fp8(
                    pfrag, bfr[ks * 4 + nt], acc[nt], 0, 0, 0);
            acc[4] = __builtin_amdgcn_mfma_f32_16x16x32_fp8_fp8(pfrag, ones, acc[4], 0, 0, 0);
        }
    }

    // write partials straight from regs: partial[js][i][68] (64 num + den)
    float* pb = partial + ((long)js * (BATCH * NPIX) + rowbase) * 68;
    #pragma unroll
    for (int nt = 0; nt < 4; ++nt)
        #pragma unroll
        for (int r = 0; r < 4; ++r)
            pb[(quad * 4 + r) * 68 + nt * 16 + l15] = acc[nt][r];
    if (l15 == 0) {
        #pragma unroll
        for (int r = 0; r < 4; ++r)
            pb[(quad * 4 + r) * 68 + 64] = acc[4][r];
    }
}

// ---------------------------------------------------------------------------
// Kernel 3: reduce 4 j-slice partials -> out = (gamma/den)*num + x
// 512 blocks x 256 thr; 8 threads per pixel row (8 channels each).
// ---------------------------------------------------------------------------
__global__ __launch_bounds__(256) void reduce_kernel(
    const float* __restrict__ partial, const float* __restrict__ x,
    const float* __restrict__ gamma_p, float* __restrict__ out)
{
    const int tid = threadIdx.x;
    const long i  = (long)blockIdx.x * 32 + (tid >> 3);
    const int c0  = (tid & 7) * 8;
    const float* p = partial + i * 68;
    float4 n0 = {0.f, 0.f, 0.f, 0.f}, n1 = {0.f, 0.f, 0.f, 0.f};
    float den = 0.f;
    #pragma unroll
    for (int js = 0; js < 4; ++js) {
        const float* pj = p + (long)js * (BATCH * NPIX) * 68;
        float4 a = *(const float4*)(pj + c0);
        float4 c = *(const float4*)(pj + c0 + 4);
        n0.x += a.x; n0.y += a.y; n0.z += a.z; n0.w += a.w;
        n1.x += c.x; n1.y += c.y; n1.z += c.z; n1.w += c.w;
        den += pj[64];
    }
    const float rd = gamma_p[0] / den;
    const float* xr = x + i * 64 + c0;
    float* orow = out + i * 64 + c0;
    float4 xa = *(const float4*)xr, xb = *(const float4*)(xr + 4);
    float4 oa, ob;
    oa.x = n0.x * rd + xa.x; oa.y = n0.y * rd + xa.y;
    oa.z = n0.z * rd + xa.z; oa.w = n0.w * rd + xa.w;
    ob.x = n1.x * rd + xb.x; ob.y = n1.y * rd + xb.y;
    ob.z = n1.z * rd + xb.z; ob.w = n1.w * rd + xb.w;
    *(float4*)orow = oa; *(float4*)(orow + 4) = ob;
}

extern "C" void kernel_launch(void* const* d_in, const int* in_sizes, int n_in,
                              void* d_out, int out_size, void* d_ws, size_t ws_size,
                              hipStream_t stream) {
    const float* x     = (const float*)d_in[0];
    const float* w_f   = (const float*)d_in[1];
    const float* b_f   = (const float*)d_in[2];
    const float* w_g   = (const float*)d_in[3];
    const float* b_g   = (const float*)d_in[4];
    const float* w_h   = (const float*)d_in[5];
    const float* b_h   = (const float*)d_in[6];
    const float* gamma = (const float*)d_in[7];
    float* out = (float*)d_out;

    bf16* fq = (bf16*)d_ws;                                // 16384*8 bf16
    bf16* gq = fq + 16384 * 8;                             // 16384*8 bf16 (x log2e)
    unsigned char* hT = (unsigned char*)(gq + 16384 * 8);  // 4*262144 fp8 (tiled)
    float* partial = (float*)(hT + (long)BATCH * HT_BATCH); // 4*16384*68 f32

    proj_kernel<<<256, 256, 0, stream>>>(x, w_f, b_f, w_g, b_g, w_h, b_h, fq, gq, hT);
    attn_kernel<<<1024, 256, 0, stream>>>(fq, gq, hT, partial);
    reduce_kernel<<<512, 256, 0, stream>>>(partial, x, gamma, out);
}

// Round 8
// 117.468 us; speedup vs baseline: 1.0058x; 1.0058x over previous
//
#include <hip/hip_runtime.h>
#include <hip/hip_bf16.h>

typedef __bf16 bf16;
typedef __bf16 bf16x8 __attribute__((ext_vector_type(8)));
typedef __bf16 bf16x4 __attribute__((ext_vector_type(4)));
typedef float floatx4 __attribute__((ext_vector_type(4)));

// may_alias: LDS P-buffer is written as int (fp8 pack) and read as long
// (MFMA fragment) with no barrier between (wave-private). Without may_alias,
// TBAA lets the compiler reorder the ds_read above the ds_write (round-3 NaN).
typedef int    aint    __attribute__((may_alias));
typedef long   along   __attribute__((may_alias));

#define NPIX 4096
#define BATCH 4
#define LOG2E 1.4426950408889634f
// hT3 layout: [b][j>>5][c][j&31] bytes; 2048 B per j32-block, 262144 B per batch
#define HT_BATCH 262144

__device__ inline bf16x8 zero8() {
    bf16x8 v;
    #pragma unroll
    for (int i = 0; i < 8; ++i) v[i] = (bf16)0.0f;
    return v;
}

// ---------------------------------------------------------------------------
// Kernel 1: projections via MFMA.  X[16384x64] @ W[64x80] ->
//   fq [16384][8] bf16, gq [16384][8] bf16 (PRE-SCALED by log2e),
//   hT3 [4][128][64][32] fp8 e4m3 (PV-B-fragment-native: one bfrag = one
//   contiguous 512-B block).
// ---------------------------------------------------------------------------
__global__ __launch_bounds__(256) void proj_kernel(
    const float* __restrict__ x,
    const float* __restrict__ w_f, const float* __restrict__ b_f,
    const float* __restrict__ w_g, const float* __restrict__ b_g,
    const float* __restrict__ w_h, const float* __restrict__ b_h,
    bf16* __restrict__ fq, bf16* __restrict__ gq, unsigned char* __restrict__ hT)
{
    __shared__ bf16 xs[64 * 72];
    __shared__ bf16 wt[80 * 72];
    __shared__ float bs[80];
    const int tid = threadIdx.x;
    const int p0 = blockIdx.x * 64;

    {   // stage x tile 64x64 f32 -> bf16
        const float4* xg = (const float4*)(x + (long)p0 * 64);
        #pragma unroll
        for (int it = 0; it < 4; ++it) {
            int i4 = tid + it * 256;
            float4 v = xg[i4];
            int row = i4 >> 4, c4 = (i4 & 15) * 4;
            bf16x4 pk;
            pk[0] = (bf16)v.x; pk[1] = (bf16)v.y; pk[2] = (bf16)v.z; pk[3] = (bf16)v.w;
            *(bf16x4*)(&xs[row * 72 + c4]) = pk;
        }
    }
    for (int idx = tid; idx < 80 * 64; idx += 256) {
        int n = idx >> 6, c = idx & 63;
        float v = (n < 8) ? w_f[c * 8 + n]
                : (n < 16) ? w_g[c * 8 + (n - 8)]
                : w_h[c * 64 + (n - 16)];
        wt[n * 72 + c] = (bf16)v;
    }
    if (tid < 80)
        bs[tid] = (tid < 8) ? b_f[tid] : (tid < 16) ? b_g[tid - 8] : b_h[tid - 16];
    __syncthreads();

    const int wv = tid >> 6, lane = tid & 63;
    const int quad = lane >> 4, l15 = lane & 15;
    const int b = blockIdx.x >> 6;
    const int n0pix = (p0 & (NPIX - 1)) + wv * 16 + quad * 4;  // pixel-in-batch

    bf16x8 a0 = *(const bf16x8*)(&xs[(wv * 16 + l15) * 72 + quad * 8]);
    bf16x8 a1 = *(const bf16x8*)(&xs[(wv * 16 + l15) * 72 + 32 + quad * 8]);

    #pragma unroll
    for (int nt = 0; nt < 5; ++nt) {
        float bias = bs[nt * 16 + l15];
        floatx4 acc = {bias, bias, bias, bias};
        bf16x8 b0 = *(const bf16x8*)(&wt[(nt * 16 + l15) * 72 + quad * 8]);
        bf16x8 b1 = *(const bf16x8*)(&wt[(nt * 16 + l15) * 72 + 32 + quad * 8]);
        acc = __builtin_amdgcn_mfma_f32_16x16x32_bf16(a0, b0, acc, 0, 0, 0);
        acc = __builtin_amdgcn_mfma_f32_16x16x32_bf16(a1, b1, acc, 0, 0, 0);
        if (nt == 0) {
            #pragma unroll
            for (int r = 0; r < 4; ++r) {
                long P = (long)p0 + wv * 16 + quad * 4 + r;
                if (l15 < 8) fq[P * 8 + l15] = (bf16)acc[r];
                else         gq[P * 8 + (l15 - 8)] = (bf16)(acc[r] * LOG2E);
            }
        } else {
            int c = nt * 16 + l15 - 16;
            int pk = __builtin_amdgcn_cvt_pk_fp8_f32(acc[0], acc[1], 0, false);
            pk     = __builtin_amdgcn_cvt_pk_fp8_f32(acc[2], acc[3], pk, true);
            *(aint*)(hT + (long)b * HT_BATCH + (n0pix >> 5) * 2048
                     + c * 32 + (n0pix & 31)) = pk;
        }
    }
}

// ---------------------------------------------------------------------------
// Kernel 2: software-PIPELINED fp8 MFMA flash attention partials.
// Grid 1024 = jsplit(4) x [B(4) x i-tiles(64)]. Block 256 = 4 independent
// waves (16 i rows each, 8 j-tiles of 128). Tiles are independent (no-rescale
// softmax) -> cross-tile pipeline: S(t+1) issues between S(t)'s P-write and
// PV(t)'s P-read (P double-buffered per wave), so the serial
// S->exp->pack->ds_write->ds_read->PV chain is covered by a full S-phase of
// independent work. bfrag global loads for PV(t) are issued BEFORE S(t+1),
// giving them an S-phase of L2-latency cover. No __syncthreads at all.
// ---------------------------------------------------------------------------
__device__ inline void load_bfr(along* bfr, const unsigned char* Hb, int t) {
    #pragma unroll
    for (int ks = 0; ks < 4; ++ks)
        #pragma unroll
        for (int nt = 0; nt < 4; ++nt)
            bfr[ks * 4 + nt] = *(const along*)(Hb + (t * 4 + ks) * 2048 + nt * 512);
}

__device__ inline void s_phase(const bf16* __restrict__ Fb, int t, bf16x8 gfrag,
                               char* Pbuf, int lane, int l15, int quad) {
    #pragma unroll
    for (int j8 = 0; j8 < 8; ++j8) {
        bf16x8 afrag = zero8();
        if (lane < 16) afrag = *(const bf16x8*)(Fb + (t * 128 + j8 * 16 + l15) * 8);
        floatx4 s = __builtin_amdgcn_mfma_f32_16x16x32_bf16(
            afrag, gfrag, (floatx4){0.f, 0.f, 0.f, 0.f}, 0, 0, 0);
        float e0 = __builtin_amdgcn_exp2f(s[0]);
        float e1 = __builtin_amdgcn_exp2f(s[1]);
        float e2 = __builtin_amdgcn_exp2f(s[2]);
        float e3 = __builtin_amdgcn_exp2f(s[3]);
        int pk = __builtin_amdgcn_cvt_pk_fp8_f32(e0, e1, 0, false);
        pk     = __builtin_amdgcn_cvt_pk_fp8_f32(e2, e3, pk, true);
        *(aint*)(Pbuf + l15 * 136 + j8 * 16 + quad * 4) = pk;
    }
}

__device__ inline void pv_phase(const char* Pbuf, const along* bfr, along ones,
                                floatx4* acc, int l15, int quad) {
    #pragma unroll
    for (int ks = 0; ks < 4; ++ks) {
        along pfrag = *(const along*)(Pbuf + l15 * 136 + ks * 32 + quad * 8);
        #pragma unroll
        for (int nt = 0; nt < 4; ++nt)
            acc[nt] = __builtin_amdgcn_mfma_f32_16x16x32_fp8_fp8(
                pfrag, bfr[ks * 4 + nt], acc[nt], 0, 0, 0);
        acc[4] = __builtin_amdgcn_mfma_f32_16x16x32_fp8_fp8(pfrag, ones, acc[4], 0, 0, 0);
    }
}

__global__ __launch_bounds__(256, 4) void attn_kernel(
    const bf16* __restrict__ fq, const bf16* __restrict__ gq,
    const unsigned char* __restrict__ hT, float* __restrict__ partial)
{
    __shared__ char smem[4 * 2 * 2176];         // 4 waves x P double-buffer
    const int tid  = threadIdx.x;
    const int wv   = tid >> 6, lane = tid & 63;
    const int quad = lane >> 4, l15 = lane & 15;
    const int js   = blockIdx.x >> 8;           // j-slice 0..3
    const int ib   = blockIdx.x & 255;
    const int b    = ib >> 6, it = ib & 63;
    const long rowbase = (long)b * NPIX + it * 64 + wv * 16;   // wave's 16 i rows
    const int jbase = js * 1024;

    // G fragment (bf16, pre-scaled by log2e): real k<8 in quad-0 lanes
    bf16x8 gfrag = zero8();
    if (lane < 16) gfrag = *(const bf16x8*)(gq + (rowbase + lane) * 8);

    const bf16* Fb = fq + ((long)b * NPIX + jbase) * 8;
    const unsigned char* Hb = hT + (long)b * HT_BATCH + (jbase >> 5) * 2048
                            + (l15 * 32 + quad * 8);   // per-lane part folded in

    floatx4 acc[5];                             // [0..3]=O channels, [4]=den
    #pragma unroll
    for (int nt = 0; nt < 5; ++nt) acc[nt] = (floatx4){0.f, 0.f, 0.f, 0.f};
    const along ones = 0x3838383838383838L;     // fp8 e4m3 1.0 x8
    char* P0 = smem + wv * 4352;
    char* P1 = P0 + 2176;

    along bfrA[16], bfrB[16];

    // pipeline prologue
    load_bfr(bfrA, Hb, 0);
    s_phase(Fb, 0, gfrag, P0, lane, l15, quad);

    // steady state: S(t+1) fills the gap between S(t)'s write and PV(t)'s read
    #pragma unroll
    for (int tt = 0; tt < 4; ++tt) {
        const int t = 2 * tt;
        if (t + 1 < 8) {
            load_bfr(bfrB, Hb, t + 1);
            s_phase(Fb, t + 1, gfrag, P1, lane, l15, quad);
        }
        asm volatile("" ::: "memory");          // P0 writes before P0 reads
        pv_phase(P0, bfrA, ones, acc, l15, quad);
        if (t + 2 < 8) {
            load_bfr(bfrA, Hb, t + 2);
            s_phase(Fb, t + 2, gfrag, P0, lane, l15, quad);
        }
        asm volatile("" ::: "memory");          // P1 writes before P1 reads
        pv_phase(P1, bfrB, ones, acc, l15, quad);
    }

    // write partials straight from regs: partial[js][i][68] (64 num + den)
    float* pb = partial + ((long)js * (BATCH * NPIX) + rowbase) * 68;
    #pragma unroll
    for (int nt = 0; nt < 4; ++nt)
        #pragma unroll
        for (int r = 0; r < 4; ++r)
            pb[(quad * 4 + r) * 68 + nt * 16 + l15] = acc[nt][r];
    if (l15 == 0) {
        #pragma unroll
        for (int r = 0; r < 4; ++r)
            pb[(quad * 4 + r) * 68 + 64] = acc[4][r];
    }
}

// ---------------------------------------------------------------------------
// Kernel 3: reduce 4 j-slice partials -> out = (gamma/den)*num + x
// 512 blocks x 256 thr; 8 threads per pixel row (8 channels each).
// ---------------------------------------------------------------------------
__global__ __launch_bounds__(256) void reduce_kernel(
    const float* __restrict__ partial, const float* __restrict__ x,
    const float* __restrict__ gamma_p, float* __restrict__ out)
{
    const int tid = threadIdx.x;
    const long i  = (long)blockIdx.x * 32 + (tid >> 3);
    const int c0  = (tid & 7) * 8;
    const float* p = partial + i * 68;
    float4 n0 = {0.f, 0.f, 0.f, 0.f}, n1 = {0.f, 0.f, 0.f, 0.f};
    float den = 0.f;
    #pragma unroll
    for (int js = 0; js < 4; ++js) {
        const float* pj = p + (long)js * (BATCH * NPIX) * 68;
        float4 a = *(const float4*)(pj + c0);
        float4 c = *(const float4*)(pj + c0 + 4);
        n0.x += a.x; n0.y += a.y; n0.z += a.z; n0.w += a.w;
        n1.x += c.x; n1.y += c.y; n1.z += c.z; n1.w += c.w;
        den += pj[64];
    }
    const float rd = gamma_p[0] / den;
    const float* xr = x + i * 64 + c0;
    float* orow = out + i * 64 + c0;
    float4 xa = *(const float4*)xr, xb = *(const float4*)(xr + 4);
    float4 oa, ob;
    oa.x = n0.x * rd + xa.x; oa.y = n0.y * rd + xa.y;
    oa.z = n0.z * rd + xa.z; oa.w = n0.w * rd + xa.w;
    ob.x = n1.x * rd + xb.x; ob.y = n1.y * rd + xb.y;
    ob.z = n1.z * rd + xb.z; ob.w = n1.w * rd + xb.w;
    *(float4*)orow = oa; *(float4*)(orow + 4) = ob;
}

extern "C" void kernel_launch(void* const* d_in, const int* in_sizes, int n_in,
                              void* d_out, int out_size, void* d_ws, size_t ws_size,
                              hipStream_t stream) {
    const float* x     = (const float*)d_in[0];
    const float* w_f   = (const float*)d_in[1];
    const float* b_f   = (const float*)d_in[2];
    const float* w_g   = (const float*)d_in[3];
    const float* b_g   = (const float*)d_in[4];
    const float* w_h   = (const float*)d_in[5];
    const float* b_h   = (const float*)d_in[6];
    const float* gamma = (const float*)d_in[7];
    float* out = (float*)d_out;

    bf16* fq = (bf16*)d_ws;                                // 16384*8 bf16
    bf16* gq = fq + 16384 * 8;                             // 16384*8 bf16 (x log2e)
    unsigned char* hT = (unsigned char*)(gq + 16384 * 8);  // 4*262144 fp8 (tiled)
    float* partial = (float*)(hT + (long)BATCH * HT_BATCH); // 4*16384*68 f32

    proj_kernel<<<256, 256, 0, stream>>>(x, w_f, b_f, w_g, b_g, w_h, b_h, fq, gq, hT);
    attn_kernel<<<1024, 256, 0, stream>>>(fq, gq, hT, partial);
    reduce_kernel<<<512, 256, 0, stream>>>(partial, x, gamma, out);
}

// Round 9
// 105.550 us; speedup vs baseline: 1.1193x; 1.1129x over previous
//
#include <hip/hip_runtime.h>
#include <hip/hip_bf16.h>

typedef __bf16 bf16;
typedef __bf16 bf16x8 __attribute__((ext_vector_type(8)));
typedef __bf16 bf16x4 __attribute__((ext_vector_type(4)));
typedef float floatx4 __attribute__((ext_vector_type(4)));

// may_alias: LDS P-buffer is written as int (fp8 pack) and read as long
// (MFMA fragment) with no barrier between (wave-private). Without may_alias,
// TBAA lets the compiler reorder the ds_read above the ds_write (round-3 NaN).
typedef int    aint    __attribute__((may_alias));
typedef long   along   __attribute__((may_alias));

#define NPIX 4096
#define BATCH 4
#define LOG2E 1.4426950408889634f
// hT3 layout: [b][j>>5][c][j&31] bytes; 2048 B per j32-block, 262144 B per batch
#define HT_BATCH 262144

__device__ inline bf16x8 zero8() {
    bf16x8 v;
    #pragma unroll
    for (int i = 0; i < 8; ++i) v[i] = (bf16)0.0f;
    return v;
}

// ---------------------------------------------------------------------------
// Kernel 1: projections via MFMA.  X[16384x64] @ W[64x80] ->
//   fq [16384][8] bf16, gq [16384][8] bf16 (PRE-SCALED by log2e),
//   hT3 [4][128][64][32] fp8 e4m3 (PV-B-fragment-native layout).
// FIX vs R2-R8: weight staging reads global LINEARLY (coalesced) and
// scatters into LDS, instead of strided global gathers (the proj sleeper).
// ---------------------------------------------------------------------------
__global__ __launch_bounds__(256) void proj_kernel(
    const float* __restrict__ x,
    const float* __restrict__ w_f, const float* __restrict__ b_f,
    const float* __restrict__ w_g, const float* __restrict__ b_g,
    const float* __restrict__ w_h, const float* __restrict__ b_h,
    bf16* __restrict__ fq, bf16* __restrict__ gq, unsigned char* __restrict__ hT)
{
    __shared__ bf16 xs[64 * 72];
    __shared__ bf16 wt[80 * 72];   // wt[n][c], n: 0-7 f, 8-15 g, 16-79 h
    __shared__ float bs[80];
    const int tid = threadIdx.x;
    const int p0 = blockIdx.x * 64;

    {   // stage x tile 64x64 f32 -> bf16 (coalesced float4)
        const float4* xg = (const float4*)(x + (long)p0 * 64);
        #pragma unroll
        for (int it = 0; it < 4; ++it) {
            int i4 = tid + it * 256;
            float4 v = xg[i4];
            int row = i4 >> 4, c4 = (i4 & 15) * 4;
            bf16x4 pk;
            pk[0] = (bf16)v.x; pk[1] = (bf16)v.y; pk[2] = (bf16)v.z; pk[3] = (bf16)v.w;
            *(bf16x4*)(&xs[row * 72 + c4]) = pk;
        }
    }
    // weights: linear coalesced reads, LDS scatter (w_* stored [c][n] row-major)
    for (int idx = tid; idx < 512; idx += 256) {
        int c = idx >> 3, n = idx & 7;
        wt[n * 72 + c]       = (bf16)w_f[idx];
        wt[(8 + n) * 72 + c] = (bf16)w_g[idx];
    }
    #pragma unroll
    for (int it = 0; it < 16; ++it) {
        int idx = tid + it * 256;               // 0..4095
        int c = idx >> 6, n = idx & 63;
        wt[(16 + n) * 72 + c] = (bf16)w_h[idx];
    }
    if (tid < 80)
        bs[tid] = (tid < 8) ? b_f[tid] : (tid < 16) ? b_g[tid - 8] : b_h[tid - 16];
    __syncthreads();

    const int wv = tid >> 6, lane = tid & 63;
    const int quad = lane >> 4, l15 = lane & 15;
    const int b = blockIdx.x >> 6;
    const int n0pix = (p0 & (NPIX - 1)) + wv * 16 + quad * 4;  // pixel-in-batch

    bf16x8 a0 = *(const bf16x8*)(&xs[(wv * 16 + l15) * 72 + quad * 8]);
    bf16x8 a1 = *(const bf16x8*)(&xs[(wv * 16 + l15) * 72 + 32 + quad * 8]);

    #pragma unroll
    for (int nt = 0; nt < 5; ++nt) {
        float bias = bs[nt * 16 + l15];
        floatx4 acc = {bias, bias, bias, bias};
        bf16x8 b0 = *(const bf16x8*)(&wt[(nt * 16 + l15) * 72 + quad * 8]);
        bf16x8 b1 = *(const bf16x8*)(&wt[(nt * 16 + l15) * 72 + 32 + quad * 8]);
        acc = __builtin_amdgcn_mfma_f32_16x16x32_bf16(a0, b0, acc, 0, 0, 0);
        acc = __builtin_amdgcn_mfma_f32_16x16x32_bf16(a1, b1, acc, 0, 0, 0);
        if (nt == 0) {
            #pragma unroll
            for (int r = 0; r < 4; ++r) {
                long P = (long)p0 + wv * 16 + quad * 4 + r;
                if (l15 < 8) fq[P * 8 + l15] = (bf16)acc[r];
                else         gq[P * 8 + (l15 - 8)] = (bf16)(acc[r] * LOG2E);
            }
        } else {
            int c = nt * 16 + l15 - 16;
            int pk = __builtin_amdgcn_cvt_pk_fp8_f32(acc[0], acc[1], 0, false);
            pk     = __builtin_amdgcn_cvt_pk_fp8_f32(acc[2], acc[3], pk, true);
            *(aint*)(hT + (long)b * HT_BATCH + (n0pix >> 5) * 2048
                     + c * 32 + (n0pix & 31)) = pk;
        }
    }
}

// ---------------------------------------------------------------------------
// Kernel 2: fp8 MFMA flash attention, IN-BLOCK j-split (no partial traffic,
// no reduce kernel). Grid 512 = B(4) x i-tiles(128 of 32 rows). Block 512 =
// 8 waves: igrp = wv&1 (16 i rows), jq = wv>>1 (j-quarter of 1024 = 8 tiles).
// Direct-global MFMA operands (hT3 fragment-native; zero in-loop barriers,
// single P buffer/wave). Epilogue: LDS 4-way jq-reduce + coalesced float4
// out = gamma*num/den + x. 2 blocks/CU (grid-limited), 16 waves/CU.
// ---------------------------------------------------------------------------
#define PBYTES 2176                 // 16 x 136 B per wave
#define REDOFF (8 * PBYTES)         // 17408
#define LDSTOT (REDOFF + 128 * 68 * 4)   // 17408 + 34816 = 52224

__global__ __launch_bounds__(512, 4) void attn_kernel(
    const bf16* __restrict__ fq, const bf16* __restrict__ gq,
    const unsigned char* __restrict__ hT, const float* __restrict__ x,
    const float* __restrict__ gamma_p, float* __restrict__ out)
{
    __shared__ char smem[LDSTOT];
    const int tid  = threadIdx.x;
    const int wv   = tid >> 6, lane = tid & 63;
    const int quad = lane >> 4, l15 = lane & 15;
    const int igrp = wv & 1, jq = wv >> 1;
    const int b    = blockIdx.x >> 7, it = blockIdx.x & 127;
    const long rowbase = (long)b * NPIX + it * 32 + igrp * 16;  // wave's 16 i rows
    const int jbase = jq * 1024;

    // G fragment (bf16, pre-scaled by log2e): real k<8 in quad-0 lanes
    bf16x8 gfrag = zero8();
    if (lane < 16) gfrag = *(const bf16x8*)(gq + (rowbase + lane) * 8);

    const bf16* Fb = fq + ((long)b * NPIX + jbase) * 8;
    const unsigned char* Hb = hT + (long)b * HT_BATCH + (jbase >> 5) * 2048
                            + (l15 * 32 + quad * 8);   // per-lane part folded in

    floatx4 acc[5];                             // [0..3]=O channels, [4]=den
    #pragma unroll
    for (int nt = 0; nt < 5; ++nt) acc[nt] = (floatx4){0.f, 0.f, 0.f, 0.f};
    const along ones = 0x3838383838383838L;     // fp8 e4m3 1.0 x8
    char* Pw = smem + wv * PBYTES;              // wave-private P: 16 x 136 B

    for (int t = 0; t < 8; ++t) {
        // bfrag loads issue first: whole S-phase of L2-latency cover
        along bfr[16];
        #pragma unroll
        for (int ks = 0; ks < 4; ++ks)
            #pragma unroll
            for (int nt = 0; nt < 4; ++nt)
                bfr[ks * 4 + nt] = *(const along*)(Hb + (t * 4 + ks) * 2048 + nt * 512);
        // --- S^T = F·G^T (bf16), exp2, pack fp8 -> P ---
        #pragma unroll
        for (int j8 = 0; j8 < 8; ++j8) {
            bf16x8 afrag = zero8();
            if (lane < 16) afrag = *(const bf16x8*)(Fb + (t * 128 + j8 * 16 + l15) * 8);
            floatx4 s = __builtin_amdgcn_mfma_f32_16x16x32_bf16(
                afrag, gfrag, (floatx4){0.f, 0.f, 0.f, 0.f}, 0, 0, 0);
            float e0 = __builtin_amdgcn_exp2f(s[0]);
            float e1 = __builtin_amdgcn_exp2f(s[1]);
            float e2 = __builtin_amdgcn_exp2f(s[2]);
            float e3 = __builtin_amdgcn_exp2f(s[3]);
            int pk = __builtin_amdgcn_cvt_pk_fp8_f32(e0, e1, 0, false);
            pk     = __builtin_amdgcn_cvt_pk_fp8_f32(e2, e3, pk, true);
            *(aint*)(Pw + l15 * 136 + j8 * 16 + quad * 4) = pk;
        }
        asm volatile("" ::: "memory");          // P writes before P reads
        // --- O += P·Ht, den += P·1 (fp8 MFMA) ---
        #pragma unroll
        for (int ks = 0; ks < 4; ++ks) {
            along pfrag = *(const along*)(Pw + l15 * 136 + ks * 32 + quad * 8);
            #pragma unroll
            for (int nt = 0; nt < 4; ++nt)
                acc[nt] = __builtin_amdgcn_mfma_f32_16x16x32_fp8_fp8(
                    pfrag, bfr[ks * 4 + nt], acc[nt], 0, 0, 0);
            acc[4] = __builtin_amdgcn_mfma_f32_16x16x32_fp8_fp8(pfrag, ones, acc[4], 0, 0, 0);
        }
        asm volatile("" ::: "memory");          // next S's P writes stay after PV reads
    }
    __syncthreads();                            // all PV done; P region now dead

    // jq partials -> red[jq][32 local rows][68] (64 num + den at 64)
    float* red = (float*)(smem + REDOFF);
    {
        const int rb = (jq * 32 + igrp * 16 + quad * 4) * 68;
        #pragma unroll
        for (int nt = 0; nt < 4; ++nt)
            #pragma unroll
            for (int r = 0; r < 4; ++r)
                red[rb + r * 68 + nt * 16 + l15] = acc[nt][r];
        if (l15 == 0) {
            #pragma unroll
            for (int r = 0; r < 4; ++r)
                red[rb + r * 68 + 64] = acc[4][r];
        }
    }
    __syncthreads();

    // epilogue: 512 thr = 32 rows x 16 col-chunks of 4; fully coalesced
    {
        const int row = tid >> 4, c0 = (tid & 15) * 4;
        float4 n = {0.f, 0.f, 0.f, 0.f};
        float den = 0.f;
        #pragma unroll
        for (int q = 0; q < 4; ++q) {
            const float* rr = red + (q * 32 + row) * 68;
            float4 v = *(const float4*)(rr + c0);
            n.x += v.x; n.y += v.y; n.z += v.z; n.w += v.w;
            den += rr[64];
        }
        const float rd = gamma_p[0] / den;
        const long off = ((long)b * NPIX + it * 32 + row) * 64 + c0;
        float4 xv = *(const float4*)(x + off);
        float4 o;
        o.x = n.x * rd + xv.x; o.y = n.y * rd + xv.y;
        o.z = n.z * rd + xv.z; o.w = n.w * rd + xv.w;
        *(float4*)(out + off) = o;
    }
}

extern "C" void kernel_launch(void* const* d_in, const int* in_sizes, int n_in,
                              void* d_out, int out_size, void* d_ws, size_t ws_size,
                              hipStream_t stream) {
    const float* x     = (const float*)d_in[0];
    const float* w_f   = (const float*)d_in[1];
    const float* b_f   = (const float*)d_in[2];
    const float* w_g   = (const float*)d_in[3];
    const float* b_g   = (const float*)d_in[4];
    const float* w_h   = (const float*)d_in[5];
    const float* b_h   = (const float*)d_in[6];
    const float* gamma = (const float*)d_in[7];
    float* out = (float*)d_out;

    bf16* fq = (bf16*)d_ws;                                // 16384*8 bf16
    bf16* gq = fq + 16384 * 8;                             // 16384*8 bf16 (x log2e)
    unsigned char* hT = (unsigned char*)(gq + 16384 * 8);  // 4*262144 fp8 (tiled)

    proj_kernel<<<256, 256, 0, stream>>>(x, w_f, b_f, w_g, b_g, w_h, b_h, fq, gq, hT);
    attn_kernel<<<512, 512, 0, stream>>>(fq, gq, hT, x, gamma, out);
}

// Round 10
// 98.920 us; speedup vs baseline: 1.1944x; 1.0670x over previous
//
#include <hip/hip_runtime.h>
#include <hip/hip_bf16.h>

typedef __bf16 bf16;
typedef __bf16 bf16x8 __attribute__((ext_vector_type(8)));
typedef __bf16 bf16x4 __attribute__((ext_vector_type(4)));
typedef float floatx4 __attribute__((ext_vector_type(4)));

typedef int  aint  __attribute__((may_alias));
typedef long along __attribute__((may_alias));

#define NPIX 4096
#define BATCH 4
#define LOG2E 1.4426950408889634f
// hT3 layout: [b][j>>5][c][j&31] bytes; 2048 B per j32-block, 262144 B per batch
#define HT_BATCH 262144

__device__ inline bf16x8 zero8() {
    bf16x8 v;
    #pragma unroll
    for (int i = 0; i < 8; ++i) v[i] = (bf16)0.0f;
    return v;
}

// ---------------------------------------------------------------------------
// Kernel 1: projections via MFMA.  X[16384x64] @ W[64x80] ->
//   fq [16384][8] bf16, gq [16384][8] bf16 (PRE-SCALED by log2e),
//   hT3 [4][128][64][32] fp8 e4m3 (PV-B-fragment-native layout).
// Weight staging: linear coalesced global reads, LDS scatter.
// ---------------------------------------------------------------------------
__global__ __launch_bounds__(256) void proj_kernel(
    const float* __restrict__ x,
    const float* __restrict__ w_f, const float* __restrict__ b_f,
    const float* __restrict__ w_g, const float* __restrict__ b_g,
    const float* __restrict__ w_h, const float* __restrict__ b_h,
    bf16* __restrict__ fq, bf16* __restrict__ gq, unsigned char* __restrict__ hT)
{
    __shared__ bf16 xs[64 * 72];
    __shared__ bf16 wt[80 * 72];   // wt[n][c], n: 0-7 f, 8-15 g, 16-79 h
    __shared__ float bs[80];
    const int tid = threadIdx.x;
    const int p0 = blockIdx.x * 64;

    {   // stage x tile 64x64 f32 -> bf16 (coalesced float4)
        const float4* xg = (const float4*)(x + (long)p0 * 64);
        #pragma unroll
        for (int it = 0; it < 4; ++it) {
            int i4 = tid + it * 256;
            float4 v = xg[i4];
            int row = i4 >> 4, c4 = (i4 & 15) * 4;
            bf16x4 pk;
            pk[0] = (bf16)v.x; pk[1] = (bf16)v.y; pk[2] = (bf16)v.z; pk[3] = (bf16)v.w;
            *(bf16x4*)(&xs[row * 72 + c4]) = pk;
        }
    }
    for (int idx = tid; idx < 512; idx += 256) {
        int c = idx >> 3, n = idx & 7;
        wt[n * 72 + c]       = (bf16)w_f[idx];
        wt[(8 + n) * 72 + c] = (bf16)w_g[idx];
    }
    #pragma unroll
    for (int it = 0; it < 16; ++it) {
        int idx = tid + it * 256;               // 0..4095
        int c = idx >> 6, n = idx & 63;
        wt[(16 + n) * 72 + c] = (bf16)w_h[idx];
    }
    if (tid < 80)
        bs[tid] = (tid < 8) ? b_f[tid] : (tid < 16) ? b_g[tid - 8] : b_h[tid - 16];
    __syncthreads();

    const int wv = tid >> 6, lane = tid & 63;
    const int quad = lane >> 4, l15 = lane & 15;
    const int b = blockIdx.x >> 6;
    const int n0pix = (p0 & (NPIX - 1)) + wv * 16 + quad * 4;  // pixel-in-batch

    bf16x8 a0 = *(const bf16x8*)(&xs[(wv * 16 + l15) * 72 + quad * 8]);
    bf16x8 a1 = *(const bf16x8*)(&xs[(wv * 16 + l15) * 72 + 32 + quad * 8]);

    #pragma unroll
    for (int nt = 0; nt < 5; ++nt) {
        float bias = bs[nt * 16 + l15];
        floatx4 acc = {bias, bias, bias, bias};
        bf16x8 b0 = *(const bf16x8*)(&wt[(nt * 16 + l15) * 72 + quad * 8]);
        bf16x8 b1 = *(const bf16x8*)(&wt[(nt * 16 + l15) * 72 + 32 + quad * 8]);
        acc = __builtin_amdgcn_mfma_f32_16x16x32_bf16(a0, b0, acc, 0, 0, 0);
        acc = __builtin_amdgcn_mfma_f32_16x16x32_bf16(a1, b1, acc, 0, 0, 0);
        if (nt == 0) {
            #pragma unroll
            for (int r = 0; r < 4; ++r) {
                long P = (long)p0 + wv * 16 + quad * 4 + r;
                if (l15 < 8) fq[P * 8 + l15] = (bf16)acc[r];
                else         gq[P * 8 + (l15 - 8)] = (bf16)(acc[r] * LOG2E);
            }
        } else {
            int c = nt * 16 + l15 - 16;
            int pk = __builtin_amdgcn_cvt_pk_fp8_f32(acc[0], acc[1], 0, false);
            pk     = __builtin_amdgcn_cvt_pk_fp8_f32(acc[2], acc[3], pk, true);
            *(aint*)(hT + (long)b * HT_BATCH + (n0pix >> 5) * 2048
                     + c * 32 + (n0pix & 31)) = pk;
        }
    }
}

// ---------------------------------------------------------------------------
// Kernel 2: fp8 MFMA flash attention, in-block j-split. Two serialization
// fixes vs R9:
//  (a) afrag loads issue BEFORE bfrag loads. vmcnt drains in ISSUE order, so
//      the old bfr-first order forced the first S-MFMA to drain all 16 bfrag
//      loads. Now queue order == consumption order (S first, PV last).
//  (b) S->PV transpose via ds_bpermute on the packed-fp8 pk regs (4 bperm +
//      2 cndmask per ks) instead of the P-LDS round-trip: no LDS P buffer,
//      no fences, no per-tile ds_write->ds_read lgkm drain.
// Grid 512 = B(4) x i-tiles(128 of 32 rows). Block 512 = 8 waves:
// igrp = wv&1 (16 i rows), jq = wv>>1 (j-quarter = 8 tiles of 128).
// Epilogue: LDS 4-way jq-reduce + coalesced float4 out = gamma*num/den + x.
// ---------------------------------------------------------------------------
__global__ __launch_bounds__(512, 4) void attn_kernel(
    const bf16* __restrict__ fq, const bf16* __restrict__ gq,
    const unsigned char* __restrict__ hT, const float* __restrict__ x,
    const float* __restrict__ gamma_p, float* __restrict__ out)
{
    __shared__ float red[128 * 68];             // 34816 B: jq partial reduce
    const int tid  = threadIdx.x;
    const int wv   = tid >> 6, lane = tid & 63;
    const int quad = lane >> 4, l15 = lane & 15;
    const int igrp = wv & 1, jq = wv >> 1;
    const int b    = blockIdx.x >> 7, it = blockIdx.x & 127;
    const long rowbase = (long)b * NPIX + it * 32 + igrp * 16;  // wave's 16 i rows
    const int jbase = jq * 1024;

    // G fragment (bf16, pre-scaled by log2e): real k<8 in quad-0 lanes
    bf16x8 gfrag = zero8();
    if (lane < 16) gfrag = *(const bf16x8*)(gq + (rowbase + lane) * 8);

    const bf16* Fb = fq + ((long)b * NPIX + jbase) * 8;
    const unsigned char* Hb = hT + (long)b * HT_BATCH + (jbase >> 5) * 2048
                            + (l15 * 32 + quad * 8);   // per-lane part folded in

    floatx4 acc[5];                             // [0..3]=O channels, [4]=den
    #pragma unroll
    for (int nt = 0; nt < 5; ++nt) acc[nt] = (floatx4){0.f, 0.f, 0.f, 0.f};
    const along ones = 0x3838383838383838L;     // fp8 e4m3 1.0 x8

    // bpermute lane algebra (constant per lane)
    const int idx_lo = (((quad & 1) * 2) * 16 + l15) * 4;  // src lane*4 (m 0..3)
    const int idx_hi = idx_lo + 64;                        // +16 lanes  (m 4..7)
    const bool sel_b = (quad >> 1) != 0;                   // pk[2ks] vs pk[2ks+1]

    for (int t = 0; t < 8; ++t) {
        // (a) afrag loads FIRST (consumed first by S)
        bf16x8 af[8];
        #pragma unroll
        for (int j8 = 0; j8 < 8; ++j8) {
            af[j8] = zero8();
            if (lane < 16)
                af[j8] = *(const bf16x8*)(Fb + (t * 128 + j8 * 16 + l15) * 8);
        }
        // bfrag loads second (consumed last by PV; stay in flight through S)
        along bfr[16];
        #pragma unroll
        for (int ks = 0; ks < 4; ++ks)
            #pragma unroll
            for (int nt = 0; nt < 4; ++nt)
                bfr[ks * 4 + nt] = *(const along*)(Hb + (t * 4 + ks) * 2048 + nt * 512);

        // --- S^T = F·G^T (bf16), exp2, pack fp8 -> pk regs ---
        int pk[8];
        #pragma unroll
        for (int j8 = 0; j8 < 8; ++j8) {
            floatx4 s = __builtin_amdgcn_mfma_f32_16x16x32_bf16(
                af[j8], gfrag, (floatx4){0.f, 0.f, 0.f, 0.f}, 0, 0, 0);
            float e0 = __builtin_amdgcn_exp2f(s[0]);
            float e1 = __builtin_amdgcn_exp2f(s[1]);
            float e2 = __builtin_amdgcn_exp2f(s[2]);
            float e3 = __builtin_amdgcn_exp2f(s[3]);
            int p = __builtin_amdgcn_cvt_pk_fp8_f32(e0, e1, 0, false);
            pk[j8] = __builtin_amdgcn_cvt_pk_fp8_f32(e2, e3, p, true);
        }
        // --- (b) in-register transpose + PV (fp8 MFMA) ---
        #pragma unroll
        for (int ks = 0; ks < 4; ++ks) {
            int pa = pk[2 * ks], pb = pk[2 * ks + 1];
            int lo0 = __builtin_amdgcn_ds_bpermute(idx_lo, pa);
            int lo1 = __builtin_amdgcn_ds_bpermute(idx_lo, pb);
            int hi0 = __builtin_amdgcn_ds_bpermute(idx_hi, pa);
            int hi1 = __builtin_amdgcn_ds_bpermute(idx_hi, pb);
            unsigned lo = (unsigned)(sel_b ? lo1 : lo0);
            unsigned hi = (unsigned)(sel_b ? hi1 : hi0);
            along pfrag = (along)(((unsigned long)hi << 32) | lo);
            #pragma unroll
            for (int nt = 0; nt < 4; ++nt)
                acc[nt] = __builtin_amdgcn_mfma_f32_16x16x32_fp8_fp8(
                    pfrag, bfr[ks * 4 + nt], acc[nt], 0, 0, 0);
            acc[4] = __builtin_amdgcn_mfma_f32_16x16x32_fp8_fp8(pfrag, ones, acc[4], 0, 0, 0);
        }
    }

    // jq partials -> red[jq][32 local rows][68] (64 num + den at 64)
    {
        const int rb = (jq * 32 + igrp * 16 + quad * 4) * 68;
        #pragma unroll
        for (int nt = 0; nt < 4; ++nt)
            #pragma unroll
            for (int r = 0; r < 4; ++r)
                red[rb + r * 68 + nt * 16 + l15] = acc[nt][r];
        if (l15 == 0) {
            #pragma unroll
            for (int r = 0; r < 4; ++r)
                red[rb + r * 68 + 64] = acc[4][r];
        }
    }
    __syncthreads();

    // epilogue: 512 thr = 32 rows x 16 col-chunks of 4; fully coalesced
    {
        const int row = tid >> 4, c0 = (tid & 15) * 4;
        float4 n = {0.f, 0.f, 0.f, 0.f};
        float den = 0.f;
        #pragma unroll
        for (int q = 0; q < 4; ++q) {
            const float* rr = red + (q * 32 + row) * 68;
            float4 v = *(const float4*)(rr + c0);
            n.x += v.x; n.y += v.y; n.z += v.z; n.w += v.w;
            den += rr[64];
        }
        const float rd = gamma_p[0] / den;
        const long off = ((long)b * NPIX + it * 32 + row) * 64 + c0;
        float4 xv = *(const float4*)(x + off);
        float4 o;
        o.x = n.x * rd + xv.x; o.y = n.y * rd + xv.y;
        o.z = n.z * rd + xv.z; o.w = n.w * rd + xv.w;
        *(float4*)(out + off) = o;
    }
}

extern "C" void kernel_launch(void* const* d_in, const int* in_sizes, int n_in,
                              void* d_out, int out_size, void* d_ws, size_t ws_size,
                              hipStream_t stream) {
    const float* x     = (const float*)d_in[0];
    const float* w_f   = (const float*)d_in[1];
    const float* b_f   = (const float*)d_in[2];
    const float* w_g   = (const float*)d_in[3];
    const float* b_g   = (const float*)d_in[4];
    const float* w_h   = (const float*)d_in[5];
    const float* b_h   = (const float*)d_in[6];
    const float* gamma = (const float*)d_in[7];
    float* out = (float*)d_out;

    bf16* fq = (bf16*)d_ws;                                // 16384*8 bf16
    bf16* gq = fq + 16384 * 8;                             // 16384*8 bf16 (x log2e)
    unsigned char* hT = (unsigned char*)(gq + 16384 * 8);  // 4*262144 fp8 (tiled)

    proj_kernel<<<256, 256, 0, stream>>>(x, w_f, b_f, w_g, b_g, w_h, b_h, fq, gq, hT);
    attn_kernel<<<512, 512, 0, stream>>>(fq, gq, hT, x, gamma, out);
}